// Round 1
// baseline (1926.318 us; speedup 1.0000x reference)
//
#include <hip/hip_runtime.h>
#include <math.h>

// Problem constants (shape-specialized to the harness inputs)
#define NB    8192   // n*t blocks
#define C_    256    // channels (LN + GEMM K)
#define V_    25     // vertices (GEMM M per block)
#define E2_   512    // inner2 (GEMM N)
#define H_    8      // heads
#define D_    32     // head dim
#define YPAD  36     // ys row stride (floats)
#define WPAD  520    // wc row stride (floats)
#define PPAD  520    // p row stride (floats)
#define KCH   8      // k-chunk depth
#define NCHUNK 32    // 256 / KCH

#define SCALE_ 0.17677669529663687f   // 32^-0.5
#define LOG2E_ 1.4426950408889634f

__global__ __launch_bounds__(256, 2)
void fused_ln_qk_attn(const float* __restrict__ x,
                      const float* __restrict__ gamma,
                      const float* __restrict__ beta,
                      const float* __restrict__ W,
                      const float* __restrict__ bias,
                      float* __restrict__ out)
{
    // LDS: GEMM phase needs ys(36,864 B) + wc(16,640 B) = 53,504 B.
    // Attention phase needs p(52,000 B) — aliased via union. 2 blocks/CU.
    __shared__ union {
        struct { float ys[C_][YPAD]; float wc[KCH][WPAD]; } g;
        struct { float p[V_][PPAD]; } a;
    } sm;
    __shared__ float s_mu[32];
    __shared__ float s_rs[32];

    const int tid = threadIdx.x;
    const int nt  = blockIdx.x;
    const int n   = nt >> 7;      // t dim = 128
    const int t   = nt & 127;
    // x[n][c][t][v]: elem offset = n*256*128*25 + c*128*25 + t*25 + v
    const int base = n * 819200 + t * 25;

    // ---------------- Phase 0: load x slice; thread tid owns channel c=tid ----
    float xv[32];
    {
        const float* xr = x + base + tid * 3200;
        #pragma unroll
        for (int v = 0; v < V_; ++v) xv[v] = xr[v];
        #pragma unroll
        for (int v = V_; v < 32; ++v) xv[v] = 0.0f;
        #pragma unroll
        for (int i = 0; i < 8; ++i) {
            float4 f;
            f.x = xv[i*4+0]; f.y = xv[i*4+1]; f.z = xv[i*4+2]; f.w = xv[i*4+3];
            *(float4*)&sm.g.ys[tid][i*4] = f;
        }
    }
    __syncthreads();

    // ---------------- LN stats: 8 threads per v row, shuffle-combine ----------
    {
        const int v = tid >> 3;   // 0..31 (25..31 are zero rows)
        const int j = tid & 7;
        float s1 = 0.0f, s2 = 0.0f;
        #pragma unroll 4
        for (int m = 0; m < 32; ++m) {
            float val = sm.g.ys[j + 8*m][v];
            s1 += val; s2 += val * val;
        }
        s1 += __shfl_xor(s1, 1); s2 += __shfl_xor(s2, 1);
        s1 += __shfl_xor(s1, 2); s2 += __shfl_xor(s2, 2);
        s1 += __shfl_xor(s1, 4); s2 += __shfl_xor(s2, 4);
        if (j == 0) {
            if (v < V_) {
                float mu  = s1 * (1.0f/256.0f);
                float var = s2 * (1.0f/256.0f) - mu * mu;
                s_mu[v] = mu;
                s_rs[v] = rsqrtf(var + 1e-5f);
            } else {
                s_mu[v] = 0.0f;
                s_rs[v] = 0.0f;
            }
        }
    }
    __syncthreads();

    // ---------------- Normalize from regs: y = (x-mu)*rstd*gamma_c + beta_c ---
    {
        const float g  = gamma[tid];
        const float be = beta[tid];
        #pragma unroll
        for (int i = 0; i < 8; ++i) {
            float4 f;
            f.x = (xv[i*4+0] - s_mu[i*4+0]) * s_rs[i*4+0] * g + be;
            f.y = (xv[i*4+1] - s_mu[i*4+1]) * s_rs[i*4+1] * g + be;
            f.z = (xv[i*4+2] - s_mu[i*4+2]) * s_rs[i*4+2] * g + be;
            f.w = (xv[i*4+3] - s_mu[i*4+3]) * s_rs[i*4+3] * g + be;
            *(float4*)&sm.g.ys[tid][i*4] = f;
        }
    }

    // ---------------- GEMM: P[v][e] = sum_c ys[c][v] * W[e][c] ---------------
    // Thread tile: 4 v-rows x 16 e-cols. eg = tid&31 (e0 = eg*16), vg = tid>>5.
    const int eg = tid & 31;
    const int vg = tid >> 5;
    const int e0 = eg * 16;
    float acc[4][16];
    #pragma unroll
    for (int a = 0; a < 4; ++a)
        #pragma unroll
        for (int bq = 0; bq < 16; ++bq) acc[a][bq] = 0.0f;

    const float* Wr0 = W + (size_t)tid * 256;
    const float* Wr1 = W + (size_t)(tid + 256) * 256;

    for (int ch = 0; ch < NCHUNK; ++ch) {
        const int kc0 = ch * KCH;
        // global loads for this chunk (issued before the barrier)
        float4 w00 = *(const float4*)(Wr0 + kc0);
        float4 w01 = *(const float4*)(Wr0 + kc0 + 4);
        float4 w10 = *(const float4*)(Wr1 + kc0);
        float4 w11 = *(const float4*)(Wr1 + kc0 + 4);
        __syncthreads();   // previous chunk's compute done (also covers normalize on ch==0)
        sm.g.wc[0][tid] = w00.x; sm.g.wc[1][tid] = w00.y;
        sm.g.wc[2][tid] = w00.z; sm.g.wc[3][tid] = w00.w;
        sm.g.wc[4][tid] = w01.x; sm.g.wc[5][tid] = w01.y;
        sm.g.wc[6][tid] = w01.z; sm.g.wc[7][tid] = w01.w;
        sm.g.wc[0][tid+256] = w10.x; sm.g.wc[1][tid+256] = w10.y;
        sm.g.wc[2][tid+256] = w10.z; sm.g.wc[3][tid+256] = w10.w;
        sm.g.wc[4][tid+256] = w11.x; sm.g.wc[5][tid+256] = w11.y;
        sm.g.wc[6][tid+256] = w11.z; sm.g.wc[7][tid+256] = w11.w;
        __syncthreads();

        #pragma unroll
        for (int kc = 0; kc < KCH; ++kc) {
            float4 av = *(const float4*)&sm.g.ys[kc0 + kc][vg * 4];
            const float* wrow = &sm.g.wc[kc][e0];
            #pragma unroll
            for (int q = 0; q < 4; ++q) {
                float4 bq = *(const float4*)(wrow + q*4);
                acc[0][q*4+0] += av.x * bq.x; acc[0][q*4+1] += av.x * bq.y;
                acc[0][q*4+2] += av.x * bq.z; acc[0][q*4+3] += av.x * bq.w;
                acc[1][q*4+0] += av.y * bq.x; acc[1][q*4+1] += av.y * bq.y;
                acc[1][q*4+2] += av.y * bq.z; acc[1][q*4+3] += av.y * bq.w;
                acc[2][q*4+0] += av.z * bq.x; acc[2][q*4+1] += av.z * bq.y;
                acc[2][q*4+2] += av.z * bq.z; acc[2][q*4+3] += av.z * bq.w;
                acc[3][q*4+0] += av.w * bq.x; acc[3][q*4+1] += av.w * bq.y;
                acc[3][q*4+2] += av.w * bq.z; acc[3][q*4+3] += av.w * bq.w;
            }
        }
    }

    // ---------------- Write P (+bias) into aliased LDS ------------------------
    __syncthreads();   // all ys/wc reads done; safe to overwrite via union
    {
        float4 bb[4];
        #pragma unroll
        for (int q = 0; q < 4; ++q) bb[q] = *(const float4*)(bias + e0 + q*4);
        #pragma unroll
        for (int vi = 0; vi < 4; ++vi) {
            const int v = vg * 4 + vi;
            if (v < V_) {
                #pragma unroll
                for (int q = 0; q < 4; ++q) {
                    float4 f;
                    f.x = acc[vi][q*4+0] + bb[q].x;
                    f.y = acc[vi][q*4+1] + bb[q].y;
                    f.z = acc[vi][q*4+2] + bb[q].z;
                    f.w = acc[vi][q*4+3] + bb[q].w;
                    *(float4*)&sm.a.p[v][e0 + q*4] = f;
                }
            }
        }
    }
    __syncthreads();

    // ---------------- Attention: thread = (h, i) row; dots + softmax ----------
    if (tid < H_ * V_) {           // 200 active
        const int h = tid / V_;
        const int i = tid - h * V_;
        const int qc  = h * D_;
        const int kcc = 256 + h * D_;

        float qv[32];
        #pragma unroll
        for (int dq = 0; dq < 8; ++dq) {
            float4 f = *(const float4*)&sm.a.p[i][qc + dq*4];
            qv[dq*4+0] = f.x; qv[dq*4+1] = f.y; qv[dq*4+2] = f.z; qv[dq*4+3] = f.w;
        }

        float s[25];
        float mx = -3.0e38f;
        #pragma unroll
        for (int j = 0; j < V_; ++j) {
            float dot = 0.0f;
            #pragma unroll
            for (int dq = 0; dq < 8; ++dq) {
                float4 f = *(const float4*)&sm.a.p[j][kcc + dq*4];
                dot += qv[dq*4+0]*f.x + qv[dq*4+1]*f.y
                     + qv[dq*4+2]*f.z + qv[dq*4+3]*f.w;
            }
            s[j] = dot * SCALE_;
            mx = fmaxf(mx, s[j]);
        }
        float sum = 0.0f;
        #pragma unroll
        for (int j = 0; j < V_; ++j) {
            s[j] = exp2f((s[j] - mx) * LOG2E_);
            sum += s[j];
        }
        const float r = 1.0f / sum;
        float* op = out + (size_t)nt * 5000 + h * 625 + i * 25;
        #pragma unroll
        for (int j = 0; j < V_; ++j) op[j] = s[j] * r;
    }
}

extern "C" void kernel_launch(void* const* d_in, const int* in_sizes, int n_in,
                              void* d_out, int out_size, void* d_ws, size_t ws_size,
                              hipStream_t stream) {
    const float* x     = (const float*)d_in[0];
    const float* gamma = (const float*)d_in[1];
    const float* beta  = (const float*)d_in[2];
    const float* W     = (const float*)d_in[3];
    const float* b     = (const float*)d_in[4];
    // d_in[5] = n_heads (fixed 8, shape-specialized)
    float* out = (float*)d_out;
    fused_ln_qk_attn<<<dim3(NB), dim3(256), 0, stream>>>(x, gamma, beta, W, b, out);
}

// Round 2
// 1416.740 us; speedup vs baseline: 1.3597x; 1.3597x over previous
//
#include <hip/hip_runtime.h>
#include <math.h>

// Problem constants (shape-specialized to the harness inputs)
#define NB    8192   // n*t blocks
#define C_    256    // channels (LN + GEMM K)
#define V_    25     // vertices (GEMM M per block)
#define E2_   512    // inner2 (GEMM N)
#define H_    8      // heads
#define D_    32     // head dim
#define YPAD  36     // ys row stride (floats)
#define WCP   513    // wc row stride (floats) — lane-stride-1 access, any pitch ok
#define PP    572    // p row stride (floats), with col swizzle e+4*(e>>5) max 571
#define KCH   8      // k-chunk depth
#define NCHUNK 32    // 256 / KCH

#define SCALE_ 0.17677669529663687f   // 32^-0.5
#define LOG2E_ 1.4426950408889634f

__global__ __launch_bounds__(256, 2)
void fused_ln_qk_attn(const float* __restrict__ x,
                      const float* __restrict__ gamma,
                      const float* __restrict__ beta,
                      const float* __restrict__ W,
                      const float* __restrict__ bias,
                      float* __restrict__ out)
{
    // LDS: GEMM phase ys(36864 B) + wc(16416 B) = 53280 B; attention p = 57200 B.
    // Union -> 57200 B, 2 blocks/CU.
    __shared__ union {
        struct { float ys[C_][YPAD]; float wc[KCH][WCP]; } g;
        struct { float p[V_][PP]; } a;
    } sm;
    __shared__ float s_mu[32];
    __shared__ float s_rs[32];

    const int tid = threadIdx.x;
    const int nt  = blockIdx.x;
    const int n   = nt >> 7;      // t dim = 128
    const int t   = nt & 127;
    // x[n][c][t][v]: elem offset = n*256*128*25 + c*128*25 + t*25 + v
    const int base = n * 819200 + t * 25;

    // ---------------- Phase 0: load x slice; thread tid owns channel c=tid ----
    float xv[32];
    {
        const float* xr = x + base + tid * 3200;
        #pragma unroll
        for (int v = 0; v < V_; ++v) xv[v] = xr[v];
        #pragma unroll
        for (int v = V_; v < 32; ++v) xv[v] = 0.0f;
        #pragma unroll
        for (int i = 0; i < 8; ++i) {
            float4 f;
            f.x = xv[i*4+0]; f.y = xv[i*4+1]; f.z = xv[i*4+2]; f.w = xv[i*4+3];
            *(float4*)&sm.g.ys[tid][i*4] = f;
        }
    }
    __syncthreads();

    // ---------------- LN stats: 8 threads per v row, shuffle-combine ----------
    // banks: ((j+8m)*36 + v)%32 = (4j+v)%32 -> 2-way max, free.
    {
        const int v = tid >> 3;   // 0..31 (25..31 are zero rows)
        const int j = tid & 7;
        float s1 = 0.0f, s2 = 0.0f;
        #pragma unroll 4
        for (int m = 0; m < 32; ++m) {
            float val = sm.g.ys[j + 8*m][v];
            s1 += val; s2 += val * val;
        }
        s1 += __shfl_xor(s1, 1); s2 += __shfl_xor(s2, 1);
        s1 += __shfl_xor(s1, 2); s2 += __shfl_xor(s2, 2);
        s1 += __shfl_xor(s1, 4); s2 += __shfl_xor(s2, 4);
        if (j == 0) {
            if (v < V_) {
                float mu  = s1 * (1.0f/256.0f);
                float var = s2 * (1.0f/256.0f) - mu * mu;
                s_mu[v] = mu;
                s_rs[v] = rsqrtf(var + 1e-5f);
            } else {
                s_mu[v] = 0.0f;
                s_rs[v] = 0.0f;
            }
        }
    }
    __syncthreads();

    // ---------------- Normalize from regs: y = (x-mu)*rstd*gamma_c + beta_c ---
    {
        const float g  = gamma[tid];
        const float be = beta[tid];
        #pragma unroll
        for (int i = 0; i < 8; ++i) {
            float4 f;
            f.x = (xv[i*4+0] - s_mu[i*4+0]) * s_rs[i*4+0] * g + be;
            f.y = (xv[i*4+1] - s_mu[i*4+1]) * s_rs[i*4+1] * g + be;
            f.z = (xv[i*4+2] - s_mu[i*4+2]) * s_rs[i*4+2] * g + be;
            f.w = (xv[i*4+3] - s_mu[i*4+3]) * s_rs[i*4+3] * g + be;
            *(float4*)&sm.g.ys[tid][i*4] = f;
        }
    }

    // ---------------- GEMM: P[v][e] = sum_c ys[c][v] * W[e][c] ---------------
    // Thread tile: 8 v-rows x 8 e-cols with STRIDE-64 e mapping (bank-conflict
    // free: lane-stride-1 LDS reads; eg & eg+32 alias 2-way = free).
    // Wave-uniform vg -> A-operand reads are pure broadcast.
    const int eg = tid & 63;
    const int vg = tid >> 6;
    const int v0 = vg * 8;
    float acc[8][8];
    #pragma unroll
    for (int a = 0; a < 8; ++a)
        #pragma unroll
        for (int u = 0; u < 8; ++u) acc[a][u] = 0.0f;

    const float* Wr0 = W + (size_t)tid * 256;
    const float* Wr1 = W + (size_t)(tid + 256) * 256;

    for (int ch = 0; ch < NCHUNK; ++ch) {
        const int kc0 = ch * KCH;
        // global loads for this chunk (issued before the barrier)
        float4 w00 = *(const float4*)(Wr0 + kc0);
        float4 w01 = *(const float4*)(Wr0 + kc0 + 4);
        float4 w10 = *(const float4*)(Wr1 + kc0);
        float4 w11 = *(const float4*)(Wr1 + kc0 + 4);
        __syncthreads();   // previous chunk's compute done (also covers normalize on ch==0)
        // scalar scatter, lane-stride 1 -> conflict-free
        sm.g.wc[0][tid] = w00.x; sm.g.wc[1][tid] = w00.y;
        sm.g.wc[2][tid] = w00.z; sm.g.wc[3][tid] = w00.w;
        sm.g.wc[4][tid] = w01.x; sm.g.wc[5][tid] = w01.y;
        sm.g.wc[6][tid] = w01.z; sm.g.wc[7][tid] = w01.w;
        sm.g.wc[0][tid+256] = w10.x; sm.g.wc[1][tid+256] = w10.y;
        sm.g.wc[2][tid+256] = w10.z; sm.g.wc[3][tid+256] = w10.w;
        sm.g.wc[4][tid+256] = w11.x; sm.g.wc[5][tid+256] = w11.y;
        sm.g.wc[6][tid+256] = w11.z; sm.g.wc[7][tid+256] = w11.w;
        __syncthreads();

        #pragma unroll
        for (int kc = 0; kc < KCH; ++kc) {
            float4 a0 = *(const float4*)&sm.g.ys[kc0 + kc][v0];
            float4 a1 = *(const float4*)&sm.g.ys[kc0 + kc][v0 + 4];
            float av[8];
            av[0]=a0.x; av[1]=a0.y; av[2]=a0.z; av[3]=a0.w;
            av[4]=a1.x; av[5]=a1.y; av[6]=a1.z; av[7]=a1.w;
            float wv[8];
            const float* wrow = &sm.g.wc[kc][eg];
            #pragma unroll
            for (int u = 0; u < 8; ++u) wv[u] = wrow[u * 64];
            #pragma unroll
            for (int vi = 0; vi < 8; ++vi)
                #pragma unroll
                for (int u = 0; u < 8; ++u)
                    acc[vi][u] += av[vi] * wv[u];
        }
    }

    // ---------------- Write P (+bias) into aliased LDS (swizzled columns) -----
    // col(e) = e + 4*(e>>5); e = eg + 64u -> col = eg + 4*(eg>>5) + 72u.
    __syncthreads();   // all ys/wc reads done; safe to overwrite via union
    {
        float bv[8];
        #pragma unroll
        for (int u = 0; u < 8; ++u) bv[u] = bias[eg + 64*u];
        const int cbase = eg + 4*(eg >> 5);
        #pragma unroll
        for (int vi = 0; vi < 8; ++vi) {
            const int v = v0 + vi;
            if (v < V_) {
                #pragma unroll
                for (int u = 0; u < 8; ++u)
                    sm.a.p[v][cbase + 72*u] = acc[vi][u] + bv[u];
            }
        }
    }
    __syncthreads();

    // ---------------- Attention: thread = (h, i) row; dots + softmax ----------
    // q cols: col(32h+d) = 36h+d ; k cols: col(256+32h+d) = 288+36h+d.
    // K-loop: j uniform, h-stride 36 ≡ 4 mod 32 -> 8 distinct bank groups,
    // conflict-free; same-(h) lanes broadcast.
    if (tid < H_ * V_) {           // 200 active
        const int h = tid / V_;
        const int i = tid - h * V_;
        const int qoff = 36 * h;
        const int koff = 288 + 36 * h;

        float qv[32];
        #pragma unroll
        for (int dq = 0; dq < 8; ++dq) {
            float4 f = *(const float4*)&sm.a.p[i][qoff + dq*4];
            qv[dq*4+0] = f.x; qv[dq*4+1] = f.y; qv[dq*4+2] = f.z; qv[dq*4+3] = f.w;
        }

        float s[25];
        float mx = -3.0e38f;
        #pragma unroll
        for (int j = 0; j < V_; ++j) {
            float dot = 0.0f;
            #pragma unroll
            for (int dq = 0; dq < 8; ++dq) {
                float4 f = *(const float4*)&sm.a.p[j][koff + dq*4];
                dot += qv[dq*4+0]*f.x + qv[dq*4+1]*f.y
                     + qv[dq*4+2]*f.z + qv[dq*4+3]*f.w;
            }
            s[j] = dot * SCALE_;
            mx = fmaxf(mx, s[j]);
        }
        float sum = 0.0f;
        #pragma unroll
        for (int j = 0; j < V_; ++j) {
            s[j] = exp2f((s[j] - mx) * LOG2E_);
            sum += s[j];
        }
        const float r = 1.0f / sum;
        float* op = out + (size_t)nt * 5000 + h * 625 + i * 25;
        #pragma unroll
        for (int j = 0; j < V_; ++j) op[j] = s[j] * r;
    }
}

extern "C" void kernel_launch(void* const* d_in, const int* in_sizes, int n_in,
                              void* d_out, int out_size, void* d_ws, size_t ws_size,
                              hipStream_t stream) {
    const float* x     = (const float*)d_in[0];
    const float* gamma = (const float*)d_in[1];
    const float* beta  = (const float*)d_in[2];
    const float* W     = (const float*)d_in[3];
    const float* b     = (const float*)d_in[4];
    // d_in[5] = n_heads (fixed 8, shape-specialized)
    float* out = (float*)d_out;
    fused_ln_qk_attn<<<dim3(NB), dim3(256), 0, stream>>>(x, gamma, beta, W, b, out);
}

// Round 3
// 1133.841 us; speedup vs baseline: 1.6989x; 1.2495x over previous
//
#include <hip/hip_runtime.h>
#include <math.h>

typedef _Float16 f16x8 __attribute__((ext_vector_type(8)));
typedef float    f32x4 __attribute__((ext_vector_type(4)));

#define NB    8192
#define V_    25
#define SCALE_ 0.17677669529663687f   // 32^-0.5
#define LOG2E_ 1.4426950408889634f

#define YS_P  264    // ysh/ysl pitch in f16 (mult of 8 -> b128-aligned frag reads)
#define WH_P  40     // wh/wl pitch in f16 (32-k chunk + 8 pad)
#define PP    572    // p pitch in f32 (col swizzle e+4*(e>>5), max 571)

struct SMem {
    union {
        float xbuf[256][36];                    // 36864 B: phase0 transpose + LN stats
        struct {
            _Float16 ysh[32][YS_P];             // 16896 B  A-operand hi  [v][c]
            _Float16 ysl[32][YS_P];             // 16896 B  A-operand lo
            _Float16 wh[256][WH_P];             // 20480 B  B-panel hi [e-local][k-local]
            _Float16 wl[256][WH_P];             // 20480 B  B-panel lo
        } g;                                    // 74752 B total
        float p[V_][PP];                        // 57200 B: attention QK buffer
    } u;
    float s_mu[32];
    float s_rs[32];
};

__global__ __launch_bounds__(256, 2)
void fused_ln_qk_attn(const float* __restrict__ x,
                      const float* __restrict__ gamma,
                      const float* __restrict__ beta,
                      const float* __restrict__ W,
                      const float* __restrict__ bias,
                      float* __restrict__ out)
{
    __shared__ SMem sm;

    const int tid  = threadIdx.x;
    const int lane = tid & 63;
    const int wv   = tid >> 6;           // wave id 0..3
    const int l15  = lane & 15;          // mfma frag row/col
    const int q4   = lane >> 4;          // mfma frag k-quad / row-quad
    const int nt   = blockIdx.x;
    const int n    = nt >> 7;
    const int t    = nt & 127;
    const int base = n * 819200 + t * 25;   // x[n][c][t][v]

    // ---------------- Phase 0: load x slice (thread owns channel c=tid) ------
    float xv[32];
    {
        const float* xr = x + base + tid * 3200;
        #pragma unroll
        for (int v = 0; v < V_; ++v) xv[v] = xr[v];
        #pragma unroll
        for (int v = V_; v < 32; ++v) xv[v] = 0.0f;
        #pragma unroll
        for (int i = 0; i < 8; ++i) {
            float4 f;
            f.x = xv[i*4+0]; f.y = xv[i*4+1]; f.z = xv[i*4+2]; f.w = xv[i*4+3];
            *(float4*)&sm.u.xbuf[tid][i*4] = f;
        }
    }
    __syncthreads();

    // ---------------- LN stats: 8 threads per v row, shuffle-combine ----------
    {
        const int v = tid >> 3;
        const int j = tid & 7;
        float s1 = 0.0f, s2 = 0.0f;
        #pragma unroll 4
        for (int m = 0; m < 32; ++m) {
            float val = sm.u.xbuf[j + 8*m][v];
            s1 += val; s2 += val * val;
        }
        s1 += __shfl_xor(s1, 1); s2 += __shfl_xor(s2, 1);
        s1 += __shfl_xor(s1, 2); s2 += __shfl_xor(s2, 2);
        s1 += __shfl_xor(s1, 4); s2 += __shfl_xor(s2, 4);
        if (j == 0) {
            if (v < V_) {
                float mu  = s1 * (1.0f/256.0f);
                float var = s2 * (1.0f/256.0f) - mu * mu;
                sm.s_mu[v] = mu;
                sm.s_rs[v] = rsqrtf(var + 1e-5f);
            } else {
                sm.s_mu[v] = 0.0f;
                sm.s_rs[v] = 0.0f;
            }
        }
    }
    __syncthreads();   // stats reads of xbuf complete -> safe to overwrite (ysh/ysl alias)

    // ---------------- Normalize + fp16 hi/lo split -> ysh/ysl[v][c] -----------
    {
        const float g  = gamma[tid];
        const float be = beta[tid];
        #pragma unroll
        for (int v = 0; v < V_; ++v) {
            float val = (xv[v] - sm.s_mu[v]) * sm.s_rs[v] * g + be;
            _Float16 h = (_Float16)val;
            sm.u.g.ysh[v][tid] = h;
            sm.u.g.ysl[v][tid] = (_Float16)(val - (float)h);
        }
        // rows 25..31 left stale: their P rows are never read (v<25 everywhere)
    }

    // bias values for this lane's 16 output columns (hoisted)
    float bv[2][4];
    #pragma unroll
    for (int half = 0; half < 2; ++half)
        #pragma unroll
        for (int j = 0; j < 4; ++j)
            bv[half][j] = bias[half*256 + (wv*4 + j)*16 + l15];

    // ---------------- GEMM: P[v][e] = sum_c ys[v][c] * W[e][c] via MFMA -------
    // fp16 split-x3: P = Ah*Bh + Al*Bh + Ah*Bl.  16x16x32_f16.
    // Per half (256 e): 8 chunks of 32 k; wave owns n-tiles wv*4..wv*4+3.
    f32x4 acc[2][2][4];   // [half][mt][nt-local]
    #pragma unroll
    for (int h = 0; h < 2; ++h)
        #pragma unroll
        for (int m = 0; m < 2; ++m)
            #pragma unroll
            for (int j = 0; j < 4; ++j)
                acc[h][m][j] = (f32x4){0.f, 0.f, 0.f, 0.f};

    for (int half = 0; half < 2; ++half) {
        const float* Wbase = W + (size_t)half * 256 * 256;
        for (int ch = 0; ch < 8; ++ch) {
            // stage: thread loads 4 pairs of float4 (32B of one W row each)
            float4 wa[4], wb[4];
            #pragma unroll
            for (int s = 0; s < 4; ++s) {
                int F2 = tid + 256*s;
                int e  = F2 >> 2, kq = F2 & 3;
                const float* p0 = Wbase + (size_t)e*256 + ch*32 + kq*8;
                wa[s] = *(const float4*)p0;
                wb[s] = *(const float4*)(p0 + 4);
            }
            __syncthreads();   // previous chunk's frag reads done
            #pragma unroll
            for (int s = 0; s < 4; ++s) {
                int F2 = tid + 256*s;
                int e  = F2 >> 2, kq = F2 & 3;
                float vals[8] = {wa[s].x, wa[s].y, wa[s].z, wa[s].w,
                                 wb[s].x, wb[s].y, wb[s].z, wb[s].w};
                f16x8 h8, l8;
                #pragma unroll
                for (int j = 0; j < 8; ++j) {
                    _Float16 hh = (_Float16)vals[j];
                    h8[j] = hh;
                    l8[j] = (_Float16)(vals[j] - (float)hh);
                }
                *(f16x8*)&sm.u.g.wh[e][kq*8] = h8;
                *(f16x8*)&sm.u.g.wl[e][kq*8] = l8;
            }
            __syncthreads();

            // A fragments: ysh/ysl[mt*16 + l15][ch*32 + q4*8 .. +7]
            f16x8 Ah[2], Al[2];
            #pragma unroll
            for (int mt = 0; mt < 2; ++mt) {
                Ah[mt] = *(const f16x8*)&sm.u.g.ysh[mt*16 + l15][ch*32 + q4*8];
                Al[mt] = *(const f16x8*)&sm.u.g.ysl[mt*16 + l15][ch*32 + q4*8];
            }
            #pragma unroll
            for (int j = 0; j < 4; ++j) {
                int erow = (wv*4 + j)*16 + l15;
                f16x8 Bh = *(const f16x8*)&sm.u.g.wh[erow][q4*8];
                f16x8 Bl = *(const f16x8*)&sm.u.g.wl[erow][q4*8];
                #pragma unroll
                for (int mt = 0; mt < 2; ++mt) {
                    acc[half][mt][j] = __builtin_amdgcn_mfma_f32_16x16x32_f16(Ah[mt], Bh, acc[half][mt][j], 0, 0, 0);
                    acc[half][mt][j] = __builtin_amdgcn_mfma_f32_16x16x32_f16(Al[mt], Bh, acc[half][mt][j], 0, 0, 0);
                    acc[half][mt][j] = __builtin_amdgcn_mfma_f32_16x16x32_f16(Ah[mt], Bl, acc[half][mt][j], 0, 0, 0);
                }
            }
        }
    }
    __syncthreads();   // all ys/wh reads done; p aliases the whole region

    // ---------------- P (+bias) -> LDS, swizzled col(e) = e + 4*(e>>5) --------
    // C/D layout: n(col)=l15, m(row)=q4*4+reg  [verified m89/m91]
    #pragma unroll
    for (int half = 0; half < 2; ++half)
        #pragma unroll
        for (int j = 0; j < 4; ++j) {
            int e   = half*256 + (wv*4 + j)*16 + l15;
            int col = e + 4*(e >> 5);
            #pragma unroll
            for (int mt = 0; mt < 2; ++mt) {
                #pragma unroll
                for (int r = 0; r < 4; ++r) {
                    int v = mt*16 + q4*4 + r;
                    if (v < V_) sm.u.p[v][col] = acc[half][mt][j][r] + bv[half][j];
                }
            }
        }
    __syncthreads();

    // ---------------- Attention: thread = (h, i) row; dots + softmax ----------
    if (tid < 8 * V_) {           // 200 active
        const int h = tid / V_;
        const int i = tid - h * V_;
        const int qoff = 36 * h;          // col(32h+d) = 36h+d
        const int koff = 288 + 36 * h;    // col(256+32h+d) = 288+36h+d

        float qv[32];
        #pragma unroll
        for (int dq = 0; dq < 8; ++dq) {
            float4 f = *(const float4*)&sm.u.p[i][qoff + dq*4];
            qv[dq*4+0] = f.x; qv[dq*4+1] = f.y; qv[dq*4+2] = f.z; qv[dq*4+3] = f.w;
        }

        float s[25];
        float mx = -3.0e38f;
        #pragma unroll
        for (int j = 0; j < V_; ++j) {
            float dot = 0.0f;
            #pragma unroll
            for (int dq = 0; dq < 8; ++dq) {
                float4 f = *(const float4*)&sm.u.p[j][koff + dq*4];
                dot += qv[dq*4+0]*f.x + qv[dq*4+1]*f.y
                     + qv[dq*4+2]*f.z + qv[dq*4+3]*f.w;
            }
            s[j] = dot * SCALE_;
            mx = fmaxf(mx, s[j]);
        }
        float sum = 0.0f;
        #pragma unroll
        for (int j = 0; j < V_; ++j) {
            s[j] = exp2f((s[j] - mx) * LOG2E_);
            sum += s[j];
        }
        const float r = 1.0f / sum;
        float* op = out + (size_t)nt * 5000 + h * 625 + i * 25;
        #pragma unroll
        for (int j = 0; j < V_; ++j) op[j] = s[j] * r;
    }
}

extern "C" void kernel_launch(void* const* d_in, const int* in_sizes, int n_in,
                              void* d_out, int out_size, void* d_ws, size_t ws_size,
                              hipStream_t stream) {
    const float* x     = (const float*)d_in[0];
    const float* gamma = (const float*)d_in[1];
    const float* beta  = (const float*)d_in[2];
    const float* W     = (const float*)d_in[3];
    const float* b     = (const float*)d_in[4];
    float* out = (float*)d_out;
    fused_ln_qk_attn<<<dim3(NB), dim3(256), 0, stream>>>(x, gamma, beta, W, b, out);
}

// Round 4
// 790.544 us; speedup vs baseline: 2.4367x; 1.4343x over previous
//
#include <hip/hip_runtime.h>
#include <math.h>
#include <stdint.h>

typedef _Float16 f16x8 __attribute__((ext_vector_type(8)));
typedef float    f32x4 __attribute__((ext_vector_type(4)));

typedef __attribute__((address_space(3))) uint32_t as3_u32;
typedef __attribute__((address_space(1))) uint32_t as1_u32;

__device__ __forceinline__ void dma16(const void* g, void* l) {
    // global -> LDS direct, 16B/lane: lds dest = wave-uniform base + lane*16
    __builtin_amdgcn_global_load_lds((const as1_u32*)g, (as3_u32*)l, 16, 0, 0);
}

#define NB    8192
#define V_    25
#define SCALE_ 0.17677669529663687f   // 32^-0.5
#define LOG2E_ 1.4426950408889634f
#define PP    516                      // p pitch (dwords); 516 % 32 = 4

// ---------------------------------------------------------------------------
// Pre-kernel: split W (512x256 fp32) into f16 hi/lo panels in d_ws, arranged
// per 32-k chunk in DMA-linear order with XOR bank swizzle.
// granule(C,e,q,part) = C*2048 + e*8 + ((q*2+part) ^ (e&7))   [16B granules]
// chunk C = half*8 + ch; element W[half*256+e][ch*32 + q*8 + j].
// ---------------------------------------------------------------------------
__global__ __launch_bounds__(256)
void prep_w(const float* __restrict__ W, _Float16* __restrict__ ws) {
    int tid = blockIdx.x * 256 + threadIdx.x;   // 16384 threads
    int q  = tid & 3;
    int e  = (tid >> 2) & 255;
    int C  = tid >> 10;                          // 0..15
    int h  = C >> 3, ch = C & 7;
    const float* src = W + (size_t)(h * 256 + e) * 256 + ch * 32 + q * 8;
    f16x8 hi, lo;
    #pragma unroll
    for (int j = 0; j < 8; ++j) {
        float w = src[j];
        _Float16 hh = (_Float16)w;
        hi[j] = hh;
        lo[j] = (_Float16)(w - (float)hh);
    }
    _Float16* base = ws + (size_t)C * 16384;     // 32768 B per chunk
    int gh = e * 8 + ((q * 2)     ^ (e & 7));
    int gl = e * 8 + ((q * 2 + 1) ^ (e & 7));
    *(f16x8*)(base + gh * 8) = hi;
    *(f16x8*)(base + gl * 8) = lo;
}

// ---------------------------------------------------------------------------
struct SMem {
    union {
        float xbuf[256][36];                    // 36864 B : phase0 + LN stats
        struct {
            _Float16 ysh[32][264];              // 16896 B : A hi [v][c]
            _Float16 ysl[32][264];              // 16896 B : A lo
            _Float16 wpan[16384];               // 32768 B : B panel (granules)
        } g;                                    // 66560 B
        float p[V_][PP];                        // 51600 B : attention buffer
    } u;
    float s_mu[32];
    float s_rs[32];
};

__global__ __launch_bounds__(256, 2)
void fused_ln_qk_attn(const float* __restrict__ x,
                      const float* __restrict__ gamma,
                      const float* __restrict__ beta,
                      const _Float16* __restrict__ wsp,
                      const float* __restrict__ bias,
                      float* __restrict__ out)
{
    __shared__ SMem sm;

    const int tid  = threadIdx.x;
    const int lane = tid & 63;
    const int wv   = tid >> 6;
    const int l15  = lane & 15;
    const int q4   = lane >> 4;
    const int nt   = blockIdx.x;
    const int n    = nt >> 7;
    const int t    = nt & 127;
    const int base = n * 819200 + t * 25;       // x[n][c][t][v]

    // ---------------- Phase 0: load x slice (thread owns channel c=tid) ------
    float xv[32];
    {
        const float* xr = x + base + tid * 3200;
        #pragma unroll
        for (int v = 0; v < V_; ++v) xv[v] = xr[v];
        #pragma unroll
        for (int v = V_; v < 32; ++v) xv[v] = 0.0f;
        #pragma unroll
        for (int i = 0; i < 8; ++i) {
            float4 f;
            f.x = xv[i*4+0]; f.y = xv[i*4+1]; f.z = xv[i*4+2]; f.w = xv[i*4+3];
            *(float4*)&sm.u.xbuf[tid][i*4] = f;
        }
    }
    __syncthreads();

    // ---------------- LN stats ------------------------------------------------
    {
        const int v = tid >> 3;
        const int j = tid & 7;
        float s1 = 0.0f, s2 = 0.0f;
        #pragma unroll 4
        for (int m = 0; m < 32; ++m) {
            float val = sm.u.xbuf[j + 8*m][v];
            s1 += val; s2 += val * val;
        }
        s1 += __shfl_xor(s1, 1); s2 += __shfl_xor(s2, 1);
        s1 += __shfl_xor(s1, 2); s2 += __shfl_xor(s2, 2);
        s1 += __shfl_xor(s1, 4); s2 += __shfl_xor(s2, 4);
        if (j == 0) {
            if (v < V_) {
                float mu  = s1 * (1.0f/256.0f);
                float var = s2 * (1.0f/256.0f) - mu * mu;
                sm.s_mu[v] = mu;
                sm.s_rs[v] = rsqrtf(var + 1e-5f);
            } else { sm.s_mu[v] = 0.0f; sm.s_rs[v] = 0.0f; }
        }
    }
    __syncthreads();   // xbuf reads done -> ysh/ysl/wpan (aliases) may be written

    // ---------------- Normalize + f16 hi/lo split -> ysh/ysl[v][c] ------------
    {
        const float g  = gamma[tid];
        const float be = beta[tid];
        #pragma unroll
        for (int v = 0; v < V_; ++v) {
            float val = (xv[v] - sm.s_mu[v]) * sm.s_rs[v] * g + be;
            _Float16 h = (_Float16)val;
            sm.u.g.ysh[v][tid] = h;
            sm.u.g.ysl[v][tid] = (_Float16)(val - (float)h);
        }
        // rows 25..31 stale: corresponding P rows never read
    }

    // bias for this lane's 16 output columns
    float bv[2][4];
    #pragma unroll
    for (int h = 0; h < 2; ++h)
        #pragma unroll
        for (int j = 0; j < 4; ++j)
            bv[h][j] = bias[h*256 + (wv*4 + j)*16 + l15];

    // B fragment pointers (chunk-independent; granule XOR -> conflict-free)
    const _Float16* Bph[4];
    const _Float16* Bpl[4];
    #pragma unroll
    for (int j = 0; j < 4; ++j) {
        int erow = (wv*4 + j)*16 + l15;
        Bph[j] = &sm.u.g.wpan[(erow*8 + ((q4*2)     ^ (erow & 7))) * 8];
        Bpl[j] = &sm.u.g.wpan[(erow*8 + ((q4*2 + 1) ^ (erow & 7))) * 8];
    }
    const char* wsrc = (const char*)wsp + (size_t)wv * 8192 + (size_t)lane * 16;
    char*       wdst = (char*)&sm.u.g.wpan[0] + wv * 8192;

    // ---------------- GEMM: P[v][e] = sum_c ys[v][c]*W[e][c], f16 split-x3 ----
    f32x4 acc[2][2][4];
    #pragma unroll
    for (int h = 0; h < 2; ++h)
        #pragma unroll
        for (int m = 0; m < 2; ++m)
            #pragma unroll
            for (int j = 0; j < 4; ++j)
                acc[h][m][j] = (f32x4){0.f, 0.f, 0.f, 0.f};

    for (int C = 0; C < 16; ++C) {
        const char* g = wsrc + (size_t)C * 32768;
        #pragma unroll
        for (int i = 0; i < 8; ++i)
            dma16(g + i * 1024, wdst + i * 1024);
        __syncthreads();   // vmcnt(0) drain -> panel visible to all waves

        const int kb = (C & 7) * 32 + q4 * 8;
        f16x8 Ah0 = *(const f16x8*)&sm.u.g.ysh[l15][kb];
        f16x8 Ah1 = *(const f16x8*)&sm.u.g.ysh[16 + l15][kb];
        f16x8 Al0 = *(const f16x8*)&sm.u.g.ysl[l15][kb];
        f16x8 Al1 = *(const f16x8*)&sm.u.g.ysl[16 + l15][kb];
        const int half = C >> 3;
        #pragma unroll
        for (int j = 0; j < 4; ++j) {
            f16x8 Bh = *(const f16x8*)Bph[j];
            f16x8 Bl = *(const f16x8*)Bpl[j];
            acc[half][0][j] = __builtin_amdgcn_mfma_f32_16x16x32_f16(Ah0, Bh, acc[half][0][j], 0, 0, 0);
            acc[half][0][j] = __builtin_amdgcn_mfma_f32_16x16x32_f16(Al0, Bh, acc[half][0][j], 0, 0, 0);
            acc[half][0][j] = __builtin_amdgcn_mfma_f32_16x16x32_f16(Ah0, Bl, acc[half][0][j], 0, 0, 0);
            acc[half][1][j] = __builtin_amdgcn_mfma_f32_16x16x32_f16(Ah1, Bh, acc[half][1][j], 0, 0, 0);
            acc[half][1][j] = __builtin_amdgcn_mfma_f32_16x16x32_f16(Al1, Bh, acc[half][1][j], 0, 0, 0);
            acc[half][1][j] = __builtin_amdgcn_mfma_f32_16x16x32_f16(Ah1, Bl, acc[half][1][j], 0, 0, 0);
        }
        __syncthreads();   // all frag reads done before next chunk's DMA
    }

    // ---------------- P (+bias) -> LDS, col = (e&~31) | (((e&31)+4*(e>>5))&31)
    // C/D layout: n(col)=l15, m(row)=q4*4+reg   [verified m89/m91]
    #pragma unroll
    for (int half = 0; half < 2; ++half)
        #pragma unroll
        for (int j = 0; j < 4; ++j) {
            int e   = half*256 + (wv*4 + j)*16 + l15;
            int col = (e & ~31) | (((e & 31) + 4*(e >> 5)) & 31);
            #pragma unroll
            for (int mt = 0; mt < 2; ++mt)
                #pragma unroll
                for (int r = 0; r < 4; ++r) {
                    int v = mt*16 + q4*4 + r;
                    if (v < V_) sm.u.p[v][col] = acc[half][mt][j][r] + bv[half][j];
                }
        }
    __syncthreads();

    // ---------------- Attention: thread = (h,i) row; dots + softmax -----------
    if (tid < 8 * V_) {            // 200 active
        const int h = tid / V_;
        const int i = tid - h * V_;

        float qv[32];
        #pragma unroll
        for (int dq = 0; dq < 8; ++dq) {
            int c = 32*h + ((4*dq + 4*h) & 31);
            float4 f = *(const float4*)&sm.u.p[i][c];
            qv[dq*4+0] = f.x; qv[dq*4+1] = f.y; qv[dq*4+2] = f.z; qv[dq*4+3] = f.w;
        }

        float s[25];
        float mx = -3.0e38f;
        #pragma unroll
        for (int j = 0; j < V_; ++j) {
            float dot = 0.0f;
            #pragma unroll
            for (int dq = 0; dq < 8; ++dq) {
                int c = 256 + 32*h + ((4*dq + 4*h) & 31);
                float4 f = *(const float4*)&sm.u.p[j][c];
                dot += qv[dq*4+0]*f.x + qv[dq*4+1]*f.y
                     + qv[dq*4+2]*f.z + qv[dq*4+3]*f.w;
            }
            s[j] = dot * SCALE_;
            mx = fmaxf(mx, s[j]);
        }
        float sum = 0.0f;
        #pragma unroll
        for (int j = 0; j < V_; ++j) {
            s[j] = exp2f((s[j] - mx) * LOG2E_);
            sum += s[j];
        }
        const float r = 1.0f / sum;
        float* op = out + (size_t)nt * 5000 + h * 625 + i * 25;
        #pragma unroll
        for (int j = 0; j < V_; ++j) op[j] = s[j] * r;
    }
}

extern "C" void kernel_launch(void* const* d_in, const int* in_sizes, int n_in,
                              void* d_out, int out_size, void* d_ws, size_t ws_size,
                              hipStream_t stream) {
    const float* x     = (const float*)d_in[0];
    const float* gamma = (const float*)d_in[1];
    const float* beta  = (const float*)d_in[2];
    const float* W     = (const float*)d_in[3];
    const float* b     = (const float*)d_in[4];
    _Float16* wsp = (_Float16*)d_ws;            // 512 KB panel cache
    float* out = (float*)d_out;

    prep_w<<<dim3(64), dim3(256), 0, stream>>>(W, wsp);
    fused_ln_qk_attn<<<dim3(NB), dim3(256), 0, stream>>>(x, gamma, beta, wsp, b, out);
}

// Round 5
// 634.593 us; speedup vs baseline: 3.0355x; 1.2457x over previous
//
#include <hip/hip_runtime.h>
#include <math.h>
#include <stdint.h>

typedef _Float16 f16x8 __attribute__((ext_vector_type(8)));
typedef float    f32x4 __attribute__((ext_vector_type(4)));

#define NB    8192
#define V_    25
#define SCALE_ 0.17677669529663687f   // 32^-0.5
#define LOG2E_ 1.4426950408889634f
#define PP    516                      // p pitch (dwords); 516 % 32 = 4

// ---------------------------------------------------------------------------
// Pre-kernel: split W (512x256 fp32) into per-lane MFMA B-fragments in d_ws.
// Tile index idx = C*16 + T2, C = half*8 + ch (k-chunk), T2 = n-tile in half.
// Block of 2048 B per idx: [0,1024) = Bh frags (64 lanes x 16B, lane-linear),
//                          [1024,2048) = Bl frags.
// Lane l -> l15=l&15, q4=l>>4; frag element jj: W[half*256 + T2*16 + l15]
//                                               [ch*32 + q4*8 + jj]
// Main kernel reads lane-linear 16B -> perfectly coalesced dwordx4, L2-hot.
// ---------------------------------------------------------------------------
__global__ __launch_bounds__(256)
void prep_w(const float* __restrict__ W, _Float16* __restrict__ ws) {
    int tid  = blockIdx.x * 256 + threadIdx.x;   // 16384 threads
    int lane = tid & 63;
    int idx  = tid >> 6;                         // 0..255
    int C    = idx >> 4;
    int T2   = idx & 15;
    int half = C >> 3, ch = C & 7;
    int l15  = lane & 15, q4 = lane >> 4;
    const float* src = W + (size_t)(half*256 + T2*16 + l15) * 256 + ch*32 + q4*8;
    f16x8 hi, lo;
    #pragma unroll
    for (int j = 0; j < 8; ++j) {
        float w = src[j];
        _Float16 hh = (_Float16)w;
        hi[j] = hh;
        lo[j] = (_Float16)(w - (float)hh);
    }
    char* base = (char*)ws + (size_t)idx * 2048 + lane * 16;
    *(f16x8*)base          = hi;
    *(f16x8*)(base + 1024) = lo;
}

// ---------------------------------------------------------------------------
struct SMem {
    union {
        float xbuf[256][36];                    // 36864 B : phase0 + LN stats
        struct {
            _Float16 ysh[32][264];              // 16896 B : A hi [v][c]
            _Float16 ysl[32][264];              // 16896 B : A lo
        } g;                                    // 33792 B
        float p[V_][PP];                        // 51600 B : attention buffer
    } u;
    float s_mu[32];
    float s_rs[32];
};

__global__ __launch_bounds__(256, 3)
void fused_ln_qk_attn(const float* __restrict__ x,
                      const float* __restrict__ gamma,
                      const float* __restrict__ beta,
                      const _Float16* __restrict__ wsp,
                      const float* __restrict__ bias,
                      float* __restrict__ out)
{
    __shared__ SMem sm;

    const int tid  = threadIdx.x;
    const int lane = tid & 63;
    const int wv   = tid >> 6;
    const int l15  = lane & 15;
    const int q4   = lane >> 4;
    const int nt   = blockIdx.x;
    const int n    = nt >> 7;
    const int t    = nt & 127;
    const int base = n * 819200 + t * 25;       // x[n][c][t][v]

    // ---------------- Phase 0: load x slice (thread owns channel c=tid) ------
    float xv[32];
    {
        const float* xr = x + base + tid * 3200;
        #pragma unroll
        for (int v = 0; v < V_; ++v) xv[v] = xr[v];
        #pragma unroll
        for (int v = V_; v < 32; ++v) xv[v] = 0.0f;
        #pragma unroll
        for (int i = 0; i < 8; ++i) {
            float4 f;
            f.x = xv[i*4+0]; f.y = xv[i*4+1]; f.z = xv[i*4+2]; f.w = xv[i*4+3];
            *(float4*)&sm.u.xbuf[tid][i*4] = f;
        }
    }
    __syncthreads();

    // ---------------- LN stats ------------------------------------------------
    {
        const int v = tid >> 3;
        const int j = tid & 7;
        float s1 = 0.0f, s2 = 0.0f;
        #pragma unroll 4
        for (int m = 0; m < 32; ++m) {
            float val = sm.u.xbuf[j + 8*m][v];
            s1 += val; s2 += val * val;
        }
        s1 += __shfl_xor(s1, 1); s2 += __shfl_xor(s2, 1);
        s1 += __shfl_xor(s1, 2); s2 += __shfl_xor(s2, 2);
        s1 += __shfl_xor(s1, 4); s2 += __shfl_xor(s2, 4);
        if (j == 0) {
            if (v < V_) {
                float mu  = s1 * (1.0f/256.0f);
                float var = s2 * (1.0f/256.0f) - mu * mu;
                sm.s_mu[v] = mu;
                sm.s_rs[v] = rsqrtf(var + 1e-5f);
            } else { sm.s_mu[v] = 0.0f; sm.s_rs[v] = 0.0f; }
        }
    }
    __syncthreads();   // xbuf reads done -> ysh/ysl (aliases) may be written

    // ---------------- Normalize + f16 hi/lo split -> ysh/ysl[v][c] ------------
    {
        const float g  = gamma[tid];
        const float be = beta[tid];
        #pragma unroll
        for (int v = 0; v < V_; ++v) {
            float val = (xv[v] - sm.s_mu[v]) * sm.s_rs[v] * g + be;
            _Float16 h = (_Float16)val;
            sm.u.g.ysh[v][tid] = h;
            sm.u.g.ysl[v][tid] = (_Float16)(val - (float)h);
        }
        // rows 25..31 stale: corresponding P rows never read
    }
    __syncthreads();   // ysh/ysl visible to all waves; K-loop is barrier-free

    // bias for this lane's 16 output columns
    float bv[2][4];
    #pragma unroll
    for (int h = 0; h < 2; ++h)
        #pragma unroll
        for (int j = 0; j < 4; ++j)
            bv[h][j] = bias[h*256 + (wv*4 + j)*16 + l15];

    // ---------------- GEMM: P[v][e] = sum_c ys[v][c]*W[e][c], f16 split-x3 ----
    // B fragments stream L2 -> VGPR directly (coalesced dwordx4, no LDS, no
    // barriers). A fragments from LDS, reused across both halves per k-chunk.
    f32x4 acc[2][2][4];
    #pragma unroll
    for (int h = 0; h < 2; ++h)
        #pragma unroll
        for (int m = 0; m < 2; ++m)
            #pragma unroll
            for (int j = 0; j < 4; ++j)
                acc[h][m][j] = (f32x4){0.f, 0.f, 0.f, 0.f};

    const char* bbase = (const char*)wsp + (size_t)lane * 16 + (size_t)(wv*4) * 2048;

    for (int ch = 0; ch < 8; ++ch) {
        const int kb = ch*32 + q4*8;
        f16x8 Ah0 = *(const f16x8*)&sm.u.g.ysh[l15][kb];
        f16x8 Ah1 = *(const f16x8*)&sm.u.g.ysh[16 + l15][kb];
        f16x8 Al0 = *(const f16x8*)&sm.u.g.ysl[l15][kb];
        f16x8 Al1 = *(const f16x8*)&sm.u.g.ysl[16 + l15][kb];
        #pragma unroll
        for (int half = 0; half < 2; ++half) {
            const char* cb = bbase + (size_t)(half*8 + ch) * 16 * 2048;
            #pragma unroll
            for (int j = 0; j < 4; ++j) {
                const char* pj = cb + (size_t)j * 2048;
                f16x8 Bh = *(const f16x8*)pj;
                f16x8 Bl = *(const f16x8*)(pj + 1024);
                acc[half][0][j] = __builtin_amdgcn_mfma_f32_16x16x32_f16(Ah0, Bh, acc[half][0][j], 0, 0, 0);
                acc[half][0][j] = __builtin_amdgcn_mfma_f32_16x16x32_f16(Al0, Bh, acc[half][0][j], 0, 0, 0);
                acc[half][0][j] = __builtin_amdgcn_mfma_f32_16x16x32_f16(Ah0, Bl, acc[half][0][j], 0, 0, 0);
                acc[half][1][j] = __builtin_amdgcn_mfma_f32_16x16x32_f16(Ah1, Bh, acc[half][1][j], 0, 0, 0);
                acc[half][1][j] = __builtin_amdgcn_mfma_f32_16x16x32_f16(Al1, Bh, acc[half][1][j], 0, 0, 0);
                acc[half][1][j] = __builtin_amdgcn_mfma_f32_16x16x32_f16(Ah1, Bl, acc[half][1][j], 0, 0, 0);
            }
        }
    }
    __syncthreads();   // all waves' ysh/ysl reads done; p aliases that region

    // ---------------- P (+bias) -> LDS, col = (e&~31) | (((e&31)+4*(e>>5))&31)
    // C/D layout: n(col)=l15, m(row)=q4*4+reg   [verified m89/m91]
    #pragma unroll
    for (int half = 0; half < 2; ++half)
        #pragma unroll
        for (int j = 0; j < 4; ++j) {
            int e   = half*256 + (wv*4 + j)*16 + l15;
            int col = (e & ~31) | (((e & 31) + 4*(e >> 5)) & 31);
            #pragma unroll
            for (int mt = 0; mt < 2; ++mt)
                #pragma unroll
                for (int r = 0; r < 4; ++r) {
                    int v = mt*16 + q4*4 + r;
                    if (v < V_) sm.u.p[v][col] = acc[half][mt][j][r] + bv[half][j];
                }
        }
    __syncthreads();

    // ---------------- Attention: thread = (h,i) row; dots + softmax -----------
    if (tid < 8 * V_) {            // 200 active
        const int h = tid / V_;
        const int i = tid - h * V_;

        float qv[32];
        #pragma unroll
        for (int dq = 0; dq < 8; ++dq) {
            int c = 32*h + ((4*dq + 4*h) & 31);
            float4 f = *(const float4*)&sm.u.p[i][c];
            qv[dq*4+0] = f.x; qv[dq*4+1] = f.y; qv[dq*4+2] = f.z; qv[dq*4+3] = f.w;
        }

        float s[25];
        float mx = -3.0e38f;
        #pragma unroll
        for (int j = 0; j < V_; ++j) {
            float dot = 0.0f;
            #pragma unroll
            for (int dq = 0; dq < 8; ++dq) {
                int c = 256 + 32*h + ((4*dq + 4*h) & 31);
                float4 f = *(const float4*)&sm.u.p[j][c];
                dot += qv[dq*4+0]*f.x + qv[dq*4+1]*f.y
                     + qv[dq*4+2]*f.z + qv[dq*4+3]*f.w;
            }
            s[j] = dot * SCALE_;
            mx = fmaxf(mx, s[j]);
        }
        float sum = 0.0f;
        #pragma unroll
        for (int j = 0; j < V_; ++j) {
            s[j] = exp2f((s[j] - mx) * LOG2E_);
            sum += s[j];
        }
        const float r = 1.0f / sum;
        float* op = out + (size_t)nt * 5000 + h * 625 + i * 25;
        #pragma unroll
        for (int j = 0; j < V_; ++j) op[j] = s[j] * r;
    }
}

extern "C" void kernel_launch(void* const* d_in, const int* in_sizes, int n_in,
                              void* d_out, int out_size, void* d_ws, size_t ws_size,
                              hipStream_t stream) {
    const float* x     = (const float*)d_in[0];
    const float* gamma = (const float*)d_in[1];
    const float* beta  = (const float*)d_in[2];
    const float* W     = (const float*)d_in[3];
    const float* b     = (const float*)d_in[4];
    _Float16* wsp = (_Float16*)d_ws;            // 512 KB fragment cache
    float* out = (float*)d_out;

    prep_w<<<dim3(64), dim3(256), 0, stream>>>(W, wsp);
    fused_ln_qk_attn<<<dim3(NB), dim3(256), 0, stream>>>(x, gamma, beta, wsp, b, out);
}